// Round 1
// baseline (907.567 us; speedup 1.0000x reference)
//
#include <hip/hip_runtime.h>
#include <hip/hip_fp16.h>
#include <stdint.h>

typedef _Float16 half2v __attribute__((ext_vector_type(2)));
typedef _Float16 half4v __attribute__((ext_vector_type(4)));
typedef _Float16 half8v __attribute__((ext_vector_type(8)));
typedef float    float4v __attribute__((ext_vector_type(4)));

#define KDIM 2048
#define PDIM 512
#define MROWS 36864   // B*F*N = 32*32*36
#define NOBJ 36
#define NTOT 2048     // 4 * PDIM concatenated outputs

// ---------------- global -> LDS direct copy, 16B per lane ----------------
__device__ __forceinline__ void gload_lds16(const void* g, void* l) {
    using gptr_t = const __attribute__((address_space(1))) unsigned int*;
    using lptr_t = __attribute__((address_space(3))) unsigned int*;
    __builtin_amdgcn_global_load_lds((gptr_t)(uintptr_t)g,
                                     (lptr_t)(uint32_t)(uintptr_t)l,
                                     16, 0, 0);
}

// ---------------- kernel 0a: x fp32 -> fp16, 8 elems/thread ----------------
__global__ __launch_bounds__(256)
void cvt_x_kernel(const float* __restrict__ x, _Float16* __restrict__ xh) {
    const size_t i = ((size_t)blockIdx.x * 256 + threadIdx.x) * 8;
    float4v a = *(const float4v*)&x[i];
    float4v b = *(const float4v*)&x[i + 4];
    half8v h;
    h[0] = (_Float16)a[0]; h[1] = (_Float16)a[1];
    h[2] = (_Float16)a[2]; h[3] = (_Float16)a[3];
    h[4] = (_Float16)b[0]; h[5] = (_Float16)b[1];
    h[6] = (_Float16)b[2]; h[7] = (_Float16)b[3];
    *(half8v*)&xh[i] = h;
}

// ------- kernel 0b: W [K][P] fp32 -> Wt [n][k] fp16 (4 mats concat on n) -------
__global__ __launch_bounds__(256)
void cvt_w_kernel(const float* __restrict__ Wp, const float* __restrict__ Ws,
                  const float* __restrict__ Wq, const float* __restrict__ Wr,
                  _Float16* __restrict__ wt) {
    const int bid = blockIdx.x;
    const int mat = bid >> 10;           // 1024 tiles per matrix (64 k-tiles x 16 p-tiles)
    const int t   = bid & 1023;
    const int kt  = t >> 4;              // 0..63
    const int pt  = t & 15;              // 0..15
    const float* W = (mat == 0) ? Wp : (mat == 1) ? Ws : (mat == 2) ? Wq : Wr;

    __shared__ float tile[32][33];
    const int tx = threadIdx.x & 31;
    const int ty = threadIdx.x >> 5;     // 0..7
    #pragma unroll
    for (int r = 0; r < 4; ++r) {
        const int k = kt * 32 + ty + r * 8;
        tile[ty + r * 8][tx] = W[(size_t)k * PDIM + pt * 32 + tx];
    }
    __syncthreads();
    #pragma unroll
    for (int r = 0; r < 4; ++r) {
        const int p = pt * 32 + ty + r * 8;
        const int n = mat * PDIM + p;
        wt[(size_t)n * KDIM + kt * 32 + tx] = (_Float16)tile[tx][ty + r * 8];
    }
}

// ---------------- kernel 1: fused 4-way projection GEMM ----------------
// C[M][2048] = A[M][2048] * Bt[n][k]^T ; 128x128 tile, BK=32, f16 MFMA 16x16x32
__global__ __launch_bounds__(256, 2)
void proj_gemm(const _Float16* __restrict__ A, const _Float16* __restrict__ Bt,
               float* __restrict__ rfeat, _Float16* __restrict__ sg,
               _Float16* __restrict__ ph, _Float16* __restrict__ vh,
               const float* __restrict__ bp, const float* __restrict__ bs,
               const float* __restrict__ bq) {
    __shared__ _Float16 sA[128 * 32];
    __shared__ _Float16 sB[128 * 32];

    const int tid  = threadIdx.x;
    const int lane = tid & 63;
    const int wave = tid >> 6;

    // col-fastest: 16 consecutive blocks share one A row-tile (L2/L3 reuse)
    const int n0 = (blockIdx.x & 15) * 128;
    const int m0 = (blockIdx.x >> 4) * 128;

    // staging: chunk c = i*256 + tid ; row = c>>2 ; kchunk = (c&3)*8 halves
    const int srow = tid >> 2;               // 0..63
    const int skc  = (tid & 3) * 8;
    const _Float16* ga0 = A  + (size_t)(m0 + srow) * KDIM + skc;
    const _Float16* ga1 = A  + (size_t)(m0 + 64 + srow) * KDIM + skc;
    const _Float16* gb0 = Bt + (size_t)(n0 + srow) * KDIM + skc;
    const _Float16* gb1 = Bt + (size_t)(n0 + 64 + srow) * KDIM + skc;

    char* lA = (char*)sA + tid * 16;
    char* lB = (char*)sB + tid * 16;

    const int m_off = (wave >> 1) * 64;
    const int n_off = (wave & 1) * 64;
    const int frow  = lane & 15;
    const int fk    = (lane >> 4) * 8;       // halves within the 32-wide K row

    float4v acc[4][4] = {};

    for (int kt = 0; kt < KDIM / 32; ++kt) {
        __syncthreads();                      // previous tile fully consumed
        gload_lds16(ga0, lA);
        gload_lds16(ga1, lA + 4096);
        gload_lds16(gb0, lB);
        gload_lds16(gb1, lB + 4096);
        ga0 += 32; ga1 += 32; gb0 += 32; gb1 += 32;
        __syncthreads();                      // vmcnt(0) drained by barrier

        half8v af[4], bf[4];
        #pragma unroll
        for (int i = 0; i < 4; ++i)
            af[i] = *(const half8v*)&sA[(m_off + i * 16 + frow) * 32 + fk];
        #pragma unroll
        for (int j = 0; j < 4; ++j)
            bf[j] = *(const half8v*)&sB[(n_off + j * 16 + frow) * 32 + fk];
        #pragma unroll
        for (int i = 0; i < 4; ++i)
            #pragma unroll
            for (int j = 0; j < 4; ++j)
                acc[i][j] = __builtin_amdgcn_mfma_f32_16x16x32_f16(af[i], bf[j], acc[i][j], 0, 0, 0);
    }

    // epilogue: block-uniform output segment (n-span 128 never crosses a 512 boundary)
    const int seg = n0 >> 9;                  // 0:proj 1:sigma 2:psi 3:r
    const int pn0 = (n0 & 511) + n_off;
    #pragma unroll
    for (int j = 0; j < 4; ++j) {
        const int pcol = pn0 + j * 16 + frow;
        float bias = 0.0f;
        if (seg == 0)      bias = bp[pcol];
        else if (seg == 1) bias = bs[pcol];
        else if (seg == 2) bias = bq[pcol];
        #pragma unroll
        for (int i = 0; i < 4; ++i) {
            const int rb = m0 + m_off + i * 16 + (lane >> 4) * 4;
            #pragma unroll
            for (int r = 0; r < 4; ++r) {
                const float val = acc[i][j][r] + bias;
                const size_t off = (size_t)(rb + r) * PDIM + pcol;
                if (seg == 0)      rfeat[off] = val;
                else if (seg == 1) sg[off] = (_Float16)val;
                else if (seg == 2) ph[off] = (_Float16)val;
                else               vh[off] = (_Float16)val;
            }
        }
    }
}

// ---------------- kernel 2: per-(b,f) attention, fp32 math ----------------
__global__ __launch_bounds__(256, 2)
void attn_kernel(const _Float16* __restrict__ sg, const _Float16* __restrict__ ph,
                 const _Float16* __restrict__ vh, float* __restrict__ rhat) {
    __shared__ _Float16 ss[NOBJ * 520];   // 512 + 8 pad halves per row
    __shared__ _Float16 ps[NOBJ * 520];
    __shared__ float    Ls[NOBJ * 37];

    const int tid = threadIdx.x;
    const size_t base = (size_t)blockIdx.x * (NOBJ * PDIM);

    for (int c = tid; c < (NOBJ * PDIM / 8); c += 256) {
        const int row = c >> 6;
        const int col = (c & 63) * 8;
        *(half8v*)&ss[row * 520 + col] = *(const half8v*)&sg[base + row * PDIM + col];
        *(half8v*)&ps[row * 520 + col] = *(const half8v*)&ph[base + row * PDIM + col];
    }
    __syncthreads();

    // logits: 12x12 grid of 3x3 register-blocked dot products (144 active threads)
    if (tid < 144) {
        const int i0 = (tid / 12) * 3;
        const int j0 = (tid % 12) * 3;
        float accv[3][3] = {};
        for (int p = 0; p < PDIM; p += 8) {
            half8v si[3], pj[3];
            #pragma unroll
            for (int ii = 0; ii < 3; ++ii) si[ii] = *(const half8v*)&ss[(i0 + ii) * 520 + p];
            #pragma unroll
            for (int jj = 0; jj < 3; ++jj) pj[jj] = *(const half8v*)&ps[(j0 + jj) * 520 + p];
            #pragma unroll
            for (int ii = 0; ii < 3; ++ii)
                #pragma unroll
                for (int jj = 0; jj < 3; ++jj) {
                    float t = accv[ii][jj];
                    #pragma unroll
                    for (int q = 0; q < 4; ++q) {
                        half2v x2; x2[0] = si[ii][2 * q]; x2[1] = si[ii][2 * q + 1];
                        half2v y2; y2[0] = pj[jj][2 * q]; y2[1] = pj[jj][2 * q + 1];
                        t = __builtin_amdgcn_fdot2(x2, y2, t, false);
                    }
                    accv[ii][jj] = t;
                }
        }
        #pragma unroll
        for (int ii = 0; ii < 3; ++ii)
            #pragma unroll
            for (int jj = 0; jj < 3; ++jj)
                Ls[(i0 + ii) * 37 + (j0 + jj)] = accv[ii][jj];
    }
    __syncthreads();

    // softmax per row (36 active threads), fp32
    if (tid < NOBJ) {
        float mx = -1e30f;
        for (int j = 0; j < NOBJ; ++j) mx = fmaxf(mx, Ls[tid * 37 + j]);
        float sum = 0.0f;
        for (int j = 0; j < NOBJ; ++j) {
            float e = __expf(Ls[tid * 37 + j] - mx);
            sum += e;
            Ls[tid * 37 + j] = e;
        }
        const float inv = 1.0f / sum;
        for (int j = 0; j < NOBJ; ++j) Ls[tid * 37 + j] *= inv;
    }
    __syncthreads();

    // AV: thread owns 4 cols (p4) x 18 rows (stride 2); v streamed from global
    const int p4 = (tid & 127) * 4;
    const int r0 = tid >> 7;
    float4v acc[18] = {};
    for (int j = 0; j < NOBJ; ++j) {
        half4v v4 = *(const half4v*)&vh[base + (size_t)j * PDIM + p4];
        float4v vf;
        vf[0] = (float)v4[0]; vf[1] = (float)v4[1];
        vf[2] = (float)v4[2]; vf[3] = (float)v4[3];
        #pragma unroll
        for (int m = 0; m < 18; ++m) {
            const float aw = Ls[(2 * m + r0) * 37 + j];
            acc[m] += aw * vf;
        }
    }
    #pragma unroll
    for (int m = 0; m < 18; ++m)
        *(float4v*)&rhat[base + (size_t)(2 * m + r0) * PDIM + p4] = acc[m];
}

extern "C" void kernel_launch(void* const* d_in, const int* in_sizes, int n_in,
                              void* d_out, int out_size, void* d_ws, size_t ws_size,
                              hipStream_t stream) {
    const float* x   = (const float*)d_in[0];
    const float* Wp  = (const float*)d_in[1];
    const float* bp  = (const float*)d_in[2];
    const float* Wsg = (const float*)d_in[3];
    const float* bsg = (const float*)d_in[4];
    const float* Wps = (const float*)d_in[5];
    const float* bps = (const float*)d_in[6];
    const float* Wr  = (const float*)d_in[7];
    float* out = (float*)d_out;

    // workspace layout (bytes): xh 150,994,944 | wt 8,388,608 | sig/psi/v 37,748,736 each
    char* ws = (char*)d_ws;
    _Float16* xh = (_Float16*)(ws);
    _Float16* wt = (_Float16*)(ws + 150994944UL);
    _Float16* sg = (_Float16*)(ws + 159383552UL);
    _Float16* ph = (_Float16*)(ws + 197132288UL);
    _Float16* vh = (_Float16*)(ws + 234881024UL);

    // M*K/8 / 256 = 36864 blocks, exact
    cvt_x_kernel<<<36864, 256, 0, stream>>>(x, xh);
    cvt_w_kernel<<<4096, 256, 0, stream>>>(Wp, Wsg, Wps, Wr, wt);
    // (M/128=288) x (NTOT/128=16) tiles
    proj_gemm<<<288 * 16, 256, 0, stream>>>(xh, wt, out, sg, ph, vh, bp, bsg, bps);
    attn_kernel<<<1024, 256, 0, stream>>>(sg, ph, vh, out + 18874368);
}